// Round 6
// baseline (2415.260 us; speedup 1.0000x reference)
//
#include <hip/hip_runtime.h>
#include <hip/hip_bf16.h>
#include <stdint.h>

typedef __bf16 bf16_t;
typedef bf16_t bf16x8 __attribute__((ext_vector_type(8)));
typedef float f32x4 __attribute__((ext_vector_type(4)));

#define IN_F 4096
#define OUT_F 4096
#define M_ROWS 8192
#define RANK 16

// ---------------------------------------------------------------------------
// Kernel 1: dequantize 4-bit -> fp32, fold LoRA (Wp = W + B*A), store bf16.
// Block covers 8 o-rows x 256 i-cols so lora_A is fetched once per block
// (16 KB) instead of once per thread-row (8x traffic cut vs r5).
// ---------------------------------------------------------------------------
__global__ __launch_bounds__(256)
void dequant_lora_kernel(const int* __restrict__ qw, const float* __restrict__ wmax,
                         const float* __restrict__ lA, const float* __restrict__ lB,
                         bf16_t* __restrict__ Wp) {
  const int bid = blockIdx.x;
  const int bo = bid >> 4;            // 0..511 (o-groups of 8)
  const int bi = bid & 15;            // 0..15  (i-groups of 256)
  const int t  = threadIdx.x;
  const int o  = bo * 8 + (t >> 5);
  const int i0 = bi * 256 + (t & 31) * 8;
  const int f0 = o * IN_F + i0;

  const int4 q4 = *(const int4*)(qw + (f0 >> 1));
  const float scale = wmax[f0 >> 6];
  const float st = scale * (2.0f / 15.0f);

  float v[8];
  {
    const int q0 = q4.x, q1 = q4.y, q2 = q4.z, q3 = q4.w;
    v[0] = (float)(q0 & 15)        * st - scale;
    v[1] = (float)((q0 >> 4) & 15) * st - scale;
    v[2] = (float)(q1 & 15)        * st - scale;
    v[3] = (float)((q1 >> 4) & 15) * st - scale;
    v[4] = (float)(q2 & 15)        * st - scale;
    v[5] = (float)((q2 >> 4) & 15) * st - scale;
    v[6] = (float)(q3 & 15)        * st - scale;
    v[7] = (float)((q3 >> 4) & 15) * st - scale;
  }

  const float* Brow = lB + o * RANK;
#pragma unroll
  for (int r = 0; r < RANK; ++r) {
    const float br = Brow[r];
    const float4 a0 = *(const float4*)(lA + r * IN_F + i0);
    const float4 a1 = *(const float4*)(lA + r * IN_F + i0 + 4);
    v[0] += br * a0.x; v[1] += br * a0.y; v[2] += br * a0.z; v[3] += br * a0.w;
    v[4] += br * a1.x; v[5] += br * a1.y; v[6] += br * a1.z; v[7] += br * a1.w;
  }

  bf16x8 ov;
#pragma unroll
  for (int j = 0; j < 8; ++j) ov[j] = (bf16_t)v[j];
  *(bf16x8*)(Wp + (size_t)f0) = ov;
}

// ---------------------------------------------------------------------------
// Kernel 2: x fp32 -> bf16 (vectorized)
// ---------------------------------------------------------------------------
__global__ __launch_bounds__(256)
void f32_to_bf16_kernel(const float* __restrict__ x, bf16_t* __restrict__ xb) {
  const size_t tid = (size_t)blockIdx.x * 256 + threadIdx.x;
  const float4 a0 = *(const float4*)(x + tid * 8);
  const float4 a1 = *(const float4*)(x + tid * 8 + 4);
  bf16x8 o;
  o[0] = (bf16_t)a0.x; o[1] = (bf16_t)a0.y; o[2] = (bf16_t)a0.z; o[3] = (bf16_t)a0.w;
  o[4] = (bf16_t)a1.x; o[5] = (bf16_t)a1.y; o[6] = (bf16_t)a1.z; o[7] = (bf16_t)a1.w;
  *(bf16x8*)(xb + tid * 8) = o;
}

// ---------------------------------------------------------------------------
// Kernel 3: 256x256 GEMM, BK=32, 64 KiB LDS -> 2 blocks/CU (the experiment).
// LDS layout: line = row-pair (128 B), slot s of line L holds pre-swizzle slot
// s^(L&7). Verified: every wave b128 frag read = 8 full 128-B lines = exactly
// 8 bank-cycles (conflict-free). Staging source pre-permuted (inverse swizzle).
// Double-buffered, stage-1-ahead (full-tile vm window), 2 barriers/tile.
// ---------------------------------------------------------------------------
__device__ __forceinline__ void gld(const bf16_t* src, char* dst) {
  __builtin_amdgcn_global_load_lds((const __attribute__((address_space(1))) void*)src,
                                   (__attribute__((address_space(3))) void*)dst, 16, 0, 0);
}

#define BARRIER() __builtin_amdgcn_s_barrier()
#define SBAR()    __builtin_amdgcn_sched_barrier(0)
#define WAIT_VM(n) asm volatile("s_waitcnt vmcnt(" #n ")" ::: "memory")

// one K-tile stage: A 16 KB (2 gloads) + B 16 KB (2 gloads)
#define STAGE(kt, buf) do { \
  gld(Asrc + (size_t)(kt) * 32,                        ldsA + (buf)*16384 + tid*16); \
  gld(Asrc + (size_t)128 * IN_F + (size_t)(kt) * 32,   ldsA + (buf)*16384 + 8192 + tid*16); \
  gld(Bsrc + (size_t)(kt) * 32,                        ldsB + (buf)*16384 + tid*16); \
  gld(Bsrc + (size_t)128 * IN_F + (size_t)(kt) * 32,   ldsB + (buf)*16384 + 8192 + tid*16); \
} while (0)

#define LDA1(buf, m) (*(const bf16x8*)(ldsA + (buf)*16384 + aBase + (m)*1024))
#define LDB1(buf, n) (*(const bf16x8*)(ldsB + (buf)*16384 + bBase + (n)*1024))

#define LOADA2(dst, m0, buf) do { dst[0] = LDA1(buf, m0); dst[1] = LDA1(buf, (m0)+1); } while (0)

#define PREFETCH(buf) do { \
  _Pragma("unroll") for (int n = 0; n < 4; ++n) bF[n] = LDB1(buf, n); \
  LOADA2(aF0, 0, buf); \
} while (0)

#define MFMA_Q(Q, AF) do { \
  SBAR(); \
  __builtin_amdgcn_s_setprio(1); \
  _Pragma("unroll") for (int mm = 0; mm < 2; ++mm) \
  _Pragma("unroll") for (int n = 0; n < 4; ++n) \
    acc[2*(Q)+mm][n] = __builtin_amdgcn_mfma_f32_16x16x32_bf16( \
        AF[mm], bF[n], acc[2*(Q)+mm][n], 0, 0, 0); \
  __builtin_amdgcn_s_setprio(0); \
} while (0)

// Full tile: stage next (into cur^1, free since last tile), 4 quads with
// reg-pipelined A frags, boundary {barrier, vm(0) after full-tile window,
// barrier}, prefetch next tile's B + first A pair.
#define TILE_FULL(CUR, tv) do { \
  STAGE((tv) + 1, (CUR) ^ 1); \
  LOADA2(aF1, 2, CUR); MFMA_Q(0, aF0); \
  LOADA2(aF0, 4, CUR); MFMA_Q(1, aF1); \
  LOADA2(aF1, 6, CUR); MFMA_Q(2, aF0); \
  MFMA_Q(3, aF1); \
  SBAR(); BARRIER(); \
  WAIT_VM(0); \
  BARRIER(); SBAR(); \
  PREFETCH((CUR) ^ 1); \
} while (0)

#define TILE_LAST(CUR) do { \
  LOADA2(aF1, 2, CUR); MFMA_Q(0, aF0); \
  LOADA2(aF0, 4, CUR); MFMA_Q(1, aF1); \
  LOADA2(aF1, 6, CUR); MFMA_Q(2, aF0); \
  MFMA_Q(3, aF1); \
} while (0)

__global__ __launch_bounds__(512, 4)
void gemm_bk32_kernel(const bf16_t* __restrict__ Xb, const bf16_t* __restrict__ Wp,
                      const float* __restrict__ bias, float* __restrict__ C) {
  __shared__ __align__(16) bf16_t As[2 * 8192];   // 32 KiB: [2buf][128 lines][128 B]
  __shared__ __align__(16) bf16_t Bs[2 * 8192];   // 32 KiB
  char* ldsA = (char*)As;
  char* ldsB = (char*)Bs;

  const int tid  = threadIdx.x;
  const int lane = tid & 63;
  const int wave = tid >> 6;
  const int wr = wave >> 2;           // 0..1 -> M half (128 rows)
  const int wc = wave & 3;            // 0..3 -> N quarter (64 cols)
  const int r16 = lane & 15;
  const int kg  = lane >> 4;          // 0..3 -> k slot (8 bf16)

  const int bid = blockIdx.x;
  const int bm = bid >> 4;            // 0..31
  const int bn = bid & 15;            // 0..15

  // --- staging source (inverse of the line/slot swizzle) ---
  // LDS byte off (per gload) = tid*16: line=tid>>3, slotIdx=tid&7.
  // pre-swizzle slot sp = slotIdx ^ (line&7); half = sp>>2; kslot = sp&3.
  // source row = line*2 + half; source col = kslot*8.
  const int sp   = (tid & 7) ^ ((tid >> 3) & 7);
  const int srow = (tid >> 3) * 2 + (sp >> 2);      // 0..127 (gload g adds 128)
  const int scol = (sp & 3) * 8;
  const bf16_t* Asrc = Xb + (size_t)(bm * 256 + srow) * IN_F + scol;
  const bf16_t* Bsrc = Wp + (size_t)(bn * 256 + srow) * IN_F + scol;

  // --- fragment-read bases (byte offsets within one 16 KiB buffer) ---
  // row R -> line R>>1 (line&7 == (r16>>1)), half R&1; slot stored at
  // ((half<<2)|kslot) ^ (line&7).
  const int slotR = (((r16 & 1) << 2) | kg) ^ (r16 >> 1);
  const int aBase = wr * 8192 + (r16 >> 1) * 128 + slotR * 16;   // + m*1024
  const int bBase = wc * 4096 + (r16 >> 1) * 128 + slotR * 16;   // + n*1024

  f32x4 acc[8][4] = {};
  bf16x8 aF0[2], aF1[2], bF[4];

  // prologue: stage tiles 0,1; prefetch tile-0 fragments
  STAGE(0, 0);
  STAGE(1, 1);
  WAIT_VM(4);                 // tile 0 landed; tile 1's 4 in flight
  BARRIER(); SBAR();
  PREFETCH(0);

  for (int tt = 0; tt < 126; tt += 2) {
    TILE_FULL(0, tt);
    TILE_FULL(1, tt + 1);
  }
  TILE_FULL(0, 126);          // stages tile 127, prefetches its fragments
  TILE_LAST(1);               // tile 127

  // epilogue: C/D layout col=lane&15, row=kg*4+reg (m89-verified)
#pragma unroll
  for (int n = 0; n < 4; ++n) {
    const int col = bn * 256 + wc * 64 + n * 16 + r16;
    const float bv = bias[col];
#pragma unroll
    for (int m = 0; m < 8; ++m) {
      const int row0 = bm * 256 + wr * 128 + m * 16 + kg * 4;
#pragma unroll
      for (int r = 0; r < 4; ++r)
        C[(size_t)(row0 + r) * OUT_F + col] = acc[m][n][r] + bv;
    }
  }
}

// ---------------------------------------------------------------------------
extern "C" void kernel_launch(void* const* d_in, const int* in_sizes, int n_in,
                              void* d_out, int out_size, void* d_ws, size_t ws_size,
                              hipStream_t stream) {
  const float* x  = (const float*)d_in[0];
  const int*   qw = (const int*)d_in[1];
  const float* wm = (const float*)d_in[2];
  const float* lA = (const float*)d_in[3];
  const float* lB = (const float*)d_in[4];
  const float* bs = (const float*)d_in[5];
  float* out = (float*)d_out;

  bf16_t* Wp = (bf16_t*)d_ws;                                        // 33.5 MB
  bf16_t* Xb = (bf16_t*)((char*)d_ws + (size_t)OUT_F * IN_F * 2);    // 67 MB

  dequant_lora_kernel<<<8192, 256, 0, stream>>>(qw, wm, lA, lB, Wp);
  f32_to_bf16_kernel<<<M_ROWS * IN_F / 8 / 256, 256, 0, stream>>>(x, Xb);
  gemm_bk32_kernel<<<(M_ROWS / 256) * (OUT_F / 256), 512, 0, stream>>>(Xb, Wp, bs, out);
}

// Round 7
// 630.085 us; speedup vs baseline: 3.8332x; 3.8332x over previous
//
#include <hip/hip_runtime.h>
#include <hip/hip_bf16.h>
#include <stdint.h>

typedef __bf16 bf16_t;
typedef bf16_t bf16x8 __attribute__((ext_vector_type(8)));
typedef float f32x4 __attribute__((ext_vector_type(4)));

#define IN_F 4096
#define OUT_F 4096
#define M_ROWS 8192
#define RANK 16

// ---------------------------------------------------------------------------
// Kernel 1: dequantize 4-bit -> fp32, fold LoRA (Wp = W + B*A), store bf16.
// Block covers 8 o-rows x 256 i-cols so lora_A is fetched once per block.
// ---------------------------------------------------------------------------
__global__ __launch_bounds__(256)
void dequant_lora_kernel(const int* __restrict__ qw, const float* __restrict__ wmax,
                         const float* __restrict__ lA, const float* __restrict__ lB,
                         bf16_t* __restrict__ Wp) {
  const int bid = blockIdx.x;
  const int bo = bid >> 4;
  const int bi = bid & 15;
  const int t  = threadIdx.x;
  const int o  = bo * 8 + (t >> 5);
  const int i0 = bi * 256 + (t & 31) * 8;
  const int f0 = o * IN_F + i0;

  const int4 q4 = *(const int4*)(qw + (f0 >> 1));
  const float scale = wmax[f0 >> 6];
  const float st = scale * (2.0f / 15.0f);

  float v[8];
  {
    const int q0 = q4.x, q1 = q4.y, q2 = q4.z, q3 = q4.w;
    v[0] = (float)(q0 & 15)        * st - scale;
    v[1] = (float)((q0 >> 4) & 15) * st - scale;
    v[2] = (float)(q1 & 15)        * st - scale;
    v[3] = (float)((q1 >> 4) & 15) * st - scale;
    v[4] = (float)(q2 & 15)        * st - scale;
    v[5] = (float)((q2 >> 4) & 15) * st - scale;
    v[6] = (float)(q3 & 15)        * st - scale;
    v[7] = (float)((q3 >> 4) & 15) * st - scale;
  }

  const float* Brow = lB + o * RANK;
#pragma unroll
  for (int r = 0; r < RANK; ++r) {
    const float br = Brow[r];
    const float4 a0 = *(const float4*)(lA + r * IN_F + i0);
    const float4 a1 = *(const float4*)(lA + r * IN_F + i0 + 4);
    v[0] += br * a0.x; v[1] += br * a0.y; v[2] += br * a0.z; v[3] += br * a0.w;
    v[4] += br * a1.x; v[5] += br * a1.y; v[6] += br * a1.z; v[7] += br * a1.w;
  }

  bf16x8 ov;
#pragma unroll
  for (int j = 0; j < 8; ++j) ov[j] = (bf16_t)v[j];
  *(bf16x8*)(Wp + (size_t)f0) = ov;
}

// ---------------------------------------------------------------------------
// Kernel 2: x fp32 -> bf16 (vectorized)
// ---------------------------------------------------------------------------
__global__ __launch_bounds__(256)
void f32_to_bf16_kernel(const float* __restrict__ x, bf16_t* __restrict__ xb) {
  const size_t tid = (size_t)blockIdx.x * 256 + threadIdx.x;
  const float4 a0 = *(const float4*)(x + tid * 8);
  const float4 a1 = *(const float4*)(x + tid * 8 + 4);
  bf16x8 o;
  o[0] = (bf16_t)a0.x; o[1] = (bf16_t)a0.y; o[2] = (bf16_t)a0.z; o[3] = (bf16_t)a0.w;
  o[4] = (bf16_t)a1.x; o[5] = (bf16_t)a1.y; o[6] = (bf16_t)a1.z; o[7] = (bf16_t)a1.w;
  *(bf16x8*)(xb + tid * 8) = o;
}

// ---------------------------------------------------------------------------
// Kernel 3: 256x256 GEMM, BK=64. A fragments DIRECT global->VGPR (prefetched
// one phase ahead; L1-resident panel slice); only B staged in LDS (64 KiB
// dbuf). B layout: 256 rows x 128 B; slot s of row r stored at s^(r&7)
// (<=2-way conflicts = free); staging source inverse-permuted.
// Counted vmcnt(4) at boundaries; never 0 until final drain.
// ---------------------------------------------------------------------------
__device__ __forceinline__ void gld(const bf16_t* src, char* dst) {
  __builtin_amdgcn_global_load_lds((const __attribute__((address_space(1))) void*)src,
                                   (__attribute__((address_space(3))) void*)dst, 16, 0, 0);
}

#define BARRIER() __builtin_amdgcn_s_barrier()
#define SBAR()    __builtin_amdgcn_sched_barrier(0)
#define WAIT_VM(n) asm volatile("s_waitcnt vmcnt(" #n ")" ::: "memory")

// B tile stage: 4 x 8KB gloads (g covers rows g*64..g*64+63)
#define STAGE_B(kt, buf) do { \
  _Pragma("unroll") for (int g = 0; g < 4; ++g) \
    gld(Bsrc + (size_t)g * 64 * IN_F + (size_t)(kt) * 64, \
        ldsB + (buf) * 32768 + g * 8192 + tid * 16); \
} while (0)

// B fragment read: row = wc*64 + n*16 + r16 (128 B/row), slot (kh*4+kg)^(r16&7)
#define LDB(buf, n, kh) \
  (*(const bf16x8*)(ldsB + (buf)*32768 + bRowB + (n)*2048 + cB##kh))

#define PREF_B(buf, BFN) do { \
  _Pragma("unroll") for (int n = 0; n < 4; ++n) { \
    BFN[n][0] = LDB(buf, n, 0); BFN[n][1] = LDB(buf, n, 1); } \
} while (0)

// A fragment prefetch (global->VGPR): quadrant Q rows (2Q..2Q+1)*16, tile tv
#define PREF_A(dst, Q, tv) do { \
  const bf16_t* _ap = Abase + (size_t)((Q) * 32) * IN_F + (tv) * 64; \
  dst[0][0] = *(const bf16x8*)(_ap); \
  dst[0][1] = *(const bf16x8*)(_ap + 32); \
  dst[1][0] = *(const bf16x8*)(_ap + (size_t)16 * IN_F); \
  dst[1][1] = *(const bf16x8*)(_ap + (size_t)16 * IN_F + 32); \
} while (0)

#define MFMA_Q(Q, AF, BF) do { \
  SBAR(); \
  __builtin_amdgcn_s_setprio(1); \
  _Pragma("unroll") for (int kh = 0; kh < 2; ++kh) \
  _Pragma("unroll") for (int mm = 0; mm < 2; ++mm) \
  _Pragma("unroll") for (int n = 0; n < 4; ++n) \
    acc[2*(Q)+mm][n] = __builtin_amdgcn_mfma_f32_16x16x32_bf16( \
        AF[mm][kh], BF[n][kh], acc[2*(Q)+mm][n], 0, 0, 0); \
  __builtin_amdgcn_s_setprio(0); \
} while (0)

#define TILE_BODY(BFC, tv) do { \
  PREF_A(aG1, 1, tv); MFMA_Q(0, aG0, BFC); \
  PREF_A(aG0, 2, tv); MFMA_Q(1, aG1, BFC); \
  PREF_A(aG1, 3, tv); MFMA_Q(2, aG0, BFC); \
  MFMA_Q(3, aG1, BFC); \
} while (0)

// Boundary: bar (all B-frag reads of cur done) -> stage t+2 into cur ->
// counted vm(4) (drains stage(t+1), leaves stage(t+2) in flight) -> bar ->
// prefetch next tile's A quadrant 0 + all B fragments.
#define TILE_END(CUR, tv, BFN) do { \
  SBAR(); BARRIER(); \
  if ((tv) < 62) { STAGE_B((tv) + 2, CUR); SBAR(); WAIT_VM(4); } \
  else           { WAIT_VM(0); } \
  SBAR(); BARRIER(); SBAR(); \
  PREF_A(aG0, 0, (tv) + 1); \
  PREF_B((CUR) ^ 1, BFN); \
} while (0)

__global__ __launch_bounds__(512, 2)
void gemm_adirect_kernel(const bf16_t* __restrict__ Xb, const bf16_t* __restrict__ Wp,
                         const float* __restrict__ bias, float* __restrict__ C) {
  __shared__ __align__(16) bf16_t Bs[2 * 16384];   // 64 KiB: [2buf][256 rows][128 B]
  char* ldsB = (char*)Bs;

  const int tid  = threadIdx.x;
  const int lane = tid & 63;
  const int wave = tid >> 6;
  const int wr = wave >> 2;           // 0..1 -> M half (128 rows)
  const int wc = wave & 3;            // 0..3 -> N quarter (64 cols)
  const int r16 = lane & 15;
  const int kg  = lane >> 4;          // 0..3

  const int bid = blockIdx.x;
  const int bm = bid >> 4;            // 0..31
  const int bn = bid & 15;            // 0..15

  // --- B staging source (inverse of slot swizzle) ---
  // dest byte (per gload) = tid*16: row = tid>>3 (0..63, +g*64), phys slot = tid&7
  // pre-swizzle slot sp = (tid&7) ^ (row&7) -> source col = sp*8
  const int sp = (tid & 7) ^ ((tid >> 3) & 7);
  const bf16_t* Bsrc = Wp + (size_t)(bn * 256 + (tid >> 3)) * IN_F + sp * 8;

  // --- B fragment-read offsets ---
  const int bRowB = (wc * 64 + r16) * 128;              // + n*2048
  const int cB0 = ((kg)     ^ (r16 & 7)) * 16;          // kh=0 slot byte
  const int cB1 = ((4 + kg) ^ (r16 & 7)) * 16;          // kh=1 slot byte

  // --- A direct-load base: row = bm*256 + wr*128 + r16, col = kg*8 ---
  const bf16_t* Abase = Xb + (size_t)(bm * 256 + wr * 128 + r16) * IN_F + kg * 8;

  f32x4 acc[8][4] = {};
  bf16x8 aG0[2][2], aG1[2][2], bFe[4][2], bFo[4][2];

  // prologue: stage B tiles 0,1; prefetch tile-0 fragments
  STAGE_B(0, 0);
  STAGE_B(1, 1);
  WAIT_VM(4);                  // tile-0 B landed; tile-1's 4 in flight
  BARRIER(); SBAR();
  PREF_A(aG0, 0, 0);
  PREF_B(0, bFe);

  for (int tt = 0; tt < 62; tt += 2) {
    TILE_BODY(bFe, tt);     TILE_END(0, tt,     bFo);
    TILE_BODY(bFo, tt + 1); TILE_END(1, tt + 1, bFe);
  }
  TILE_BODY(bFe, 62); TILE_END(0, 62, bFo);   // drains, prefetches tile 63
  TILE_BODY(bFo, 63);                          // last tile

  // epilogue: C/D layout col=lane&15, row=kg*4+reg (m89-verified)
#pragma unroll
  for (int n = 0; n < 4; ++n) {
    const int col = bn * 256 + wc * 64 + n * 16 + r16;
    const float bv = bias[col];
#pragma unroll
    for (int m = 0; m < 8; ++m) {
      const int row0 = bm * 256 + wr * 128 + m * 16 + kg * 4;
#pragma unroll
      for (int r = 0; r < 4; ++r)
        C[(size_t)(row0 + r) * OUT_F + col] = acc[m][n][r] + bv;
    }
  }
}

// ---------------------------------------------------------------------------
extern "C" void kernel_launch(void* const* d_in, const int* in_sizes, int n_in,
                              void* d_out, int out_size, void* d_ws, size_t ws_size,
                              hipStream_t stream) {
  const float* x  = (const float*)d_in[0];
  const int*   qw = (const int*)d_in[1];
  const float* wm = (const float*)d_in[2];
  const float* lA = (const float*)d_in[3];
  const float* lB = (const float*)d_in[4];
  const float* bs = (const float*)d_in[5];
  float* out = (float*)d_out;

  bf16_t* Wp = (bf16_t*)d_ws;                                        // 33.5 MB
  bf16_t* Xb = (bf16_t*)((char*)d_ws + (size_t)OUT_F * IN_F * 2);    // 67 MB

  dequant_lora_kernel<<<8192, 256, 0, stream>>>(qw, wm, lA, lB, Wp);
  f32_to_bf16_kernel<<<M_ROWS * IN_F / 8 / 256, 256, 0, stream>>>(x, Xb);
  gemm_adirect_kernel<<<(M_ROWS / 256) * (OUT_F / 256), 512, 0, stream>>>(Xb, Wp, bs, out);
}

// Round 8
// 329.849 us; speedup vs baseline: 7.3223x; 1.9102x over previous
//
#include <hip/hip_runtime.h>
#include <hip/hip_bf16.h>
#include <stdint.h>

typedef __bf16 bf16_t;
typedef bf16_t bf16x8 __attribute__((ext_vector_type(8)));
typedef float f32x4 __attribute__((ext_vector_type(4)));

#define IN_F 4096
#define OUT_F 4096
#define M_ROWS 8192
#define RANK 16

// ---------------------------------------------------------------------------
// Kernel 1: dequantize 4-bit -> fp32, fold LoRA (Wp = W + B*A), store bf16.
// Block covers 8 o-rows x 256 i-cols so lora_A is fetched once per block.
// ---------------------------------------------------------------------------
__global__ __launch_bounds__(256)
void dequant_lora_kernel(const int* __restrict__ qw, const float* __restrict__ wmax,
                         const float* __restrict__ lA, const float* __restrict__ lB,
                         bf16_t* __restrict__ Wp) {
  const int bid = blockIdx.x;
  const int bo = bid >> 4;
  const int bi = bid & 15;
  const int t  = threadIdx.x;
  const int o  = bo * 8 + (t >> 5);
  const int i0 = bi * 256 + (t & 31) * 8;
  const int f0 = o * IN_F + i0;

  const int4 q4 = *(const int4*)(qw + (f0 >> 1));
  const float scale = wmax[f0 >> 6];
  const float st = scale * (2.0f / 15.0f);

  float v[8];
  {
    const int q0 = q4.x, q1 = q4.y, q2 = q4.z, q3 = q4.w;
    v[0] = (float)(q0 & 15)        * st - scale;
    v[1] = (float)((q0 >> 4) & 15) * st - scale;
    v[2] = (float)(q1 & 15)        * st - scale;
    v[3] = (float)((q1 >> 4) & 15) * st - scale;
    v[4] = (float)(q2 & 15)        * st - scale;
    v[5] = (float)((q2 >> 4) & 15) * st - scale;
    v[6] = (float)(q3 & 15)        * st - scale;
    v[7] = (float)((q3 >> 4) & 15) * st - scale;
  }

  const float* Brow = lB + o * RANK;
#pragma unroll
  for (int r = 0; r < RANK; ++r) {
    const float br = Brow[r];
    const float4 a0 = *(const float4*)(lA + r * IN_F + i0);
    const float4 a1 = *(const float4*)(lA + r * IN_F + i0 + 4);
    v[0] += br * a0.x; v[1] += br * a0.y; v[2] += br * a0.z; v[3] += br * a0.w;
    v[4] += br * a1.x; v[5] += br * a1.y; v[6] += br * a1.z; v[7] += br * a1.w;
  }

  bf16x8 ov;
#pragma unroll
  for (int j = 0; j < 8; ++j) ov[j] = (bf16_t)v[j];
  *(bf16x8*)(Wp + (size_t)f0) = ov;
}

// ---------------------------------------------------------------------------
// Kernel 2: x fp32 -> bf16 (vectorized)
// ---------------------------------------------------------------------------
__global__ __launch_bounds__(256)
void f32_to_bf16_kernel(const float* __restrict__ x, bf16_t* __restrict__ xb) {
  const size_t tid = (size_t)blockIdx.x * 256 + threadIdx.x;
  const float4 a0 = *(const float4*)(x + tid * 8);
  const float4 a1 = *(const float4*)(x + tid * 8 + 4);
  bf16x8 o;
  o[0] = (bf16_t)a0.x; o[1] = (bf16_t)a0.y; o[2] = (bf16_t)a0.z; o[3] = (bf16_t)a0.w;
  o[4] = (bf16_t)a1.x; o[5] = (bf16_t)a1.y; o[6] = (bf16_t)a1.z; o[7] = (bf16_t)a1.w;
  *(bf16x8*)(xb + tid * 8) = o;
}

// ---------------------------------------------------------------------------
// Kernel 3: 256x256 8-phase GEMM with the VERBATIM m201 LDS layout:
//   per buf: [2 half][128 rows][64 cols] bf16, byte = half*16K + swz(r*128+c*2)
//   swz(b) = b ^ (((b>>9)&1)<<5)    (st_16x32)
//   linear gload dest (tid*16) + inverse-swz SOURCE col + swz on READ.
// Schedule = r2 (template-equivalent): 4 phases/K-tile, counted vmcnt(4),
// setprio around MFMA, bijective XCD blockIdx swizzle (512 % 8 == 0).
// ---------------------------------------------------------------------------
__device__ __forceinline__ void gld(const bf16_t* src, char* dst) {
  __builtin_amdgcn_global_load_lds((const __attribute__((address_space(1))) void*)src,
                                   (__attribute__((address_space(3))) void*)dst, 16, 0, 0);
}

#define BARRIER() __builtin_amdgcn_s_barrier()
#define WAIT_LGKM0() do { asm volatile("s_waitcnt lgkmcnt(0)" ::: "memory"); \
                          __builtin_amdgcn_sched_barrier(0); } while (0)
#define WAIT_VM(n) asm volatile("s_waitcnt vmcnt(" #n ")" ::: "memory")

#define LDA(buf, m, cb) (*(const bf16x8*)(ldsA + ((buf)*32768 + aRowB + (m)*2048 + (cb))))
#define LDB(buf, n, cb) (*(const bf16x8*)(ldsB + ((buf)*32768 + bRowB + (n)*2048 + (cb))))

#define STAGE_A(kt, buf) do { \
  _Pragma("unroll") for (int g = 0; g < 4; ++g) \
    gld(Asrc + ((size_t)g*64*IN_F + (size_t)(kt)*64), ldsA + ((buf)*32768 + g*8192 + tid*16)); \
} while (0)
#define STAGE_B_HALF(kt, buf, h) do { \
  _Pragma("unroll") for (int g = 0; g < 2; ++g) \
    gld(Bsrc + ((size_t)((h)*2+g)*64*IN_F + (size_t)(kt)*64), \
        ldsB + ((buf)*32768 + ((h)*2+g)*8192 + tid*16)); \
} while (0)
#define STAGE_B(kt, buf) do { STAGE_B_HALF(kt, buf, 0); STAGE_B_HALF(kt, buf, 1); } while (0)

#define READ_B_ALL(buf) do { \
  _Pragma("unroll") for (int n = 0; n < 4; ++n) { \
    b[n][0] = LDB(buf, n, cS0); b[n][1] = LDB(buf, n, cS1); } \
} while (0)

#define PHASE(Q, EXTRA, STAGE, TAILWAIT) do { \
  a[0][0] = LDA(cur, 2*(Q),   cS0); a[0][1] = LDA(cur, 2*(Q),   cS1); \
  a[1][0] = LDA(cur, 2*(Q)+1, cS0); a[1][1] = LDA(cur, 2*(Q)+1, cS1); \
  EXTRA; STAGE; \
  BARRIER(); \
  WAIT_LGKM0(); \
  __builtin_amdgcn_s_setprio(1); \
  _Pragma("unroll") for (int kh = 0; kh < 2; ++kh) \
    _Pragma("unroll") for (int mm = 0; mm < 2; ++mm) \
      _Pragma("unroll") for (int n = 0; n < 4; ++n) \
        acc[2*(Q)+mm][n] = __builtin_amdgcn_mfma_f32_16x16x32_bf16( \
            a[mm][kh], b[n][kh], acc[2*(Q)+mm][n], 0, 0, 0); \
  __builtin_amdgcn_s_setprio(0); \
  TAILWAIT; \
  BARRIER(); \
} while (0)

__global__ __launch_bounds__(512, 2)
void gemm_m201_kernel(const bf16_t* __restrict__ Xb, const bf16_t* __restrict__ Wp,
                      const float* __restrict__ bias, float* __restrict__ C) {
  __shared__ __align__(16) bf16_t As[2 * 16384];   // [2buf][2half][128][64] swizzled
  __shared__ __align__(16) bf16_t Bs[2 * 16384];
  char* ldsA = (char*)As;
  char* ldsB = (char*)Bs;

  const int tid  = threadIdx.x;
  const int lane = tid & 63;
  const int wave = tid >> 6;
  const int wr = wave >> 2;           // 0..1 -> M half
  const int wc = wave & 3;            // 0..3 -> N quarter
  const int r16 = lane & 15;
  const int kg  = lane >> 4;          // 0..3

  // bijective XCD swizzle (nwg=512, 512%8==0): contiguous 64-wgid chunk/XCD
  const int bid  = blockIdx.x;
  const int wgid = (bid & 7) * 64 + (bid >> 3);
  const int bm = wgid >> 4;           // 0..31
  const int bn = wgid & 15;           // 0..15

  // staging: linear dest tid*16; source = inverse-st_16x32 of that dest
  const int srow = tid >> 3;                                   // 0..63 (+g*64)
  const int scol = ((tid & 7) * 8) ^ (((tid >> 5) & 1) << 4);  // element col
  const bf16_t* Asrc = Xb + (size_t)(bm * 256 + srow) * IN_F + scol;
  const bf16_t* Bsrc = Wp + (size_t)(bn * 256 + srow) * IN_F + scol;

  // read-side: byte = half*16384 + rho*128 + ((kh*64 + kg*16) ^ ((r16&4)<<3))
  const int aRowB = wr * 16384 + r16 * 128;                        // + m*2048
  const int bRowB = (wc >> 1) * 16384 + (wc & 1) * 8192 + r16 * 128; // + n*2048
  const int cS0 = (kg * 16) ^ ((r16 & 4) << 3);
  const int cS1 = cS0 + 64;

  f32x4 acc[8][4] = {};
  bf16x8 a[2][2], b[4][2];

  // prologue: stage K-tiles 0 and 1
  STAGE_A(0, 0); STAGE_B(0, 0);
  STAGE_A(1, 1); STAGE_B(1, 1);
  WAIT_VM(8);            // tile 0 landed; tile 1's 8 loads in flight
  BARRIER();

  for (int t = 0; t < 64; ++t) {
    const int cur = t & 1;
    PHASE(0, READ_B_ALL(cur),
          { if (t >= 1 && t < 63) STAGE_A(t + 1, cur ^ 1); }, {});
    PHASE(1, {},
          { if (t < 62) STAGE_B_HALF(t + 2, cur, 0); }, {});
    PHASE(2, {},
          { if (t < 62) STAGE_B_HALF(t + 2, cur, 1); }, {});
    PHASE(3, {}, {},
          { if (t < 62) { WAIT_VM(4); } else if (t == 62) { WAIT_VM(0); } });
  }

  // epilogue: C/D layout col=lane&15, row=kg*4+reg (m89-verified)
#pragma unroll
  for (int n = 0; n < 4; ++n) {
    const int col = bn * 256 + wc * 64 + n * 16 + r16;
    const float bv = bias[col];
#pragma unroll
    for (int m = 0; m < 8; ++m) {
      const int row0 = bm * 256 + wr * 128 + m * 16 + kg * 4;
#pragma unroll
      for (int r = 0; r < 4; ++r)
        C[(size_t)(row0 + r) * OUT_F + col] = acc[m][n][r] + bv;
    }
  }
}

// ---------------------------------------------------------------------------
extern "C" void kernel_launch(void* const* d_in, const int* in_sizes, int n_in,
                              void* d_out, int out_size, void* d_ws, size_t ws_size,
                              hipStream_t stream) {
  const float* x  = (const float*)d_in[0];
  const int*   qw = (const int*)d_in[1];
  const float* wm = (const float*)d_in[2];
  const float* lA = (const float*)d_in[3];
  const float* lB = (const float*)d_in[4];
  const float* bs = (const float*)d_in[5];
  float* out = (float*)d_out;

  bf16_t* Wp = (bf16_t*)d_ws;                                        // 33.5 MB
  bf16_t* Xb = (bf16_t*)((char*)d_ws + (size_t)OUT_F * IN_F * 2);    // 67 MB

  dequant_lora_kernel<<<8192, 256, 0, stream>>>(qw, wm, lA, lB, Wp);
  f32_to_bf16_kernel<<<M_ROWS * IN_F / 8 / 256, 256, 0, stream>>>(x, Xb);
  gemm_m201_kernel<<<(M_ROWS / 256) * (OUT_F / 256), 512, 0, stream>>>(Xb, Wp, bs, out);
}